// Round 1
// baseline (1537.675 us; speedup 1.0000x reference)
//
#include <hip/hip_runtime.h>
#include <stdint.h>

#define NS 150
#define D_IN 1024
#define D_H 512
#define D_OUT 256
#define BATCH 32

// ---- workspace layout (float offsets) ----
#define OFF_XT    0u                // 1024*32      = 32768   xT[i][b]
#define OFF_MUT1  32768u            // 1024*512     = 524288  muT1[i][h]
#define OFF_STDT1 557056u           // 524288               stdT1[i][h]
#define OFF_MUT2  1081344u          // 512*256      = 131072  muT2[hh][o]
#define OFF_STDT2 1212416u          // 131072               stdT2[hh][o]
#define OFF_B1S   1343488u          // 150*512      = 76800   b1s[n][h]
#define OFF_B2S   1420288u          // 150*256      = 38400   b2s[n][o]
#define OFF_HT    1458688u          // 150*512*32   = 2457600 hT[n][h][b]
// total = 3,916,288 floats = 15.7 MB

// ---------- threefry-2x32 (JAX-exact, 20 rounds) ----------
__host__ __device__ __forceinline__ void threefry2x32(uint32_t k0, uint32_t k1,
                                                      uint32_t x0, uint32_t x1,
                                                      uint32_t& o0, uint32_t& o1) {
  uint32_t k2 = k0 ^ k1 ^ 0x1BD11BDAu;
  x0 += k0; x1 += k1;
#define TFR(r) { x0 += x1; x1 = (x1 << r) | (x1 >> (32 - r)); x1 ^= x0; }
  TFR(13) TFR(15) TFR(26) TFR(6)
  x0 += k1; x1 += k2 + 1u;
  TFR(17) TFR(29) TFR(16) TFR(24)
  x0 += k2; x1 += k0 + 2u;
  TFR(13) TFR(15) TFR(26) TFR(6)
  x0 += k0; x1 += k1 + 3u;
  TFR(17) TFR(29) TFR(16) TFR(24)
  x0 += k1; x1 += k2 + 4u;
  TFR(13) TFR(15) TFR(26) TFR(6)
  x0 += k2; x1 += k0 + 5u;
#undef TFR
  o0 = x0; o1 = x1;
}

// XLA ErfInv32 (Giles polynomial)
__device__ __forceinline__ float erfinv_f(float x) {
  float w = -log1pf(-x * x);
  float p;
  if (w < 5.0f) {
    w = w - 2.5f;
    p = 2.81022636e-08f;
    p = fmaf(p, w, 3.43273939e-07f);
    p = fmaf(p, w, -3.5233877e-06f);
    p = fmaf(p, w, -4.39150654e-06f);
    p = fmaf(p, w, 0.00021858087f);
    p = fmaf(p, w, -0.00125372503f);
    p = fmaf(p, w, -0.00417768164f);
    p = fmaf(p, w, 0.246640727f);
    p = fmaf(p, w, 1.50140941f);
  } else {
    w = sqrtf(w) - 3.0f;
    p = -0.000200214257f;
    p = fmaf(p, w, 0.000100950558f);
    p = fmaf(p, w, 0.00134934322f);
    p = fmaf(p, w, -0.00367342844f);
    p = fmaf(p, w, 0.00573950773f);
    p = fmaf(p, w, -0.0076224613f);
    p = fmaf(p, w, 0.00943887047f);
    p = fmaf(p, w, 1.00167406f);
    p = fmaf(p, w, 2.83297682f);
  }
  return p * x;
}

// jax.random.normal element at flat index idx, partitionable path:
// bits = fold_in(xor) of threefry((k0,k1), (0, idx)); uniform in [lo, 1); sqrt2*erfinv
__device__ __forceinline__ float tf_normal(uint32_t k0, uint32_t k1, uint32_t idx) {
  uint32_t o0, o1;
  threefry2x32(k0, k1, 0u, idx, o0, o1);
  uint32_t bits = o0 ^ o1;
  uint32_t fb = (bits >> 9) | 0x3F800000u;
  float f = __uint_as_float(fb) - 1.0f;          // [0,1)
  const float lo = -0.99999994f;                 // nextafter(-1,0) in fp32
  float u = fmaf(f, 2.0f, lo);                   // maxval-minval rounds to 2.0f exactly
  u = fmaxf(u, lo);
  return 1.41421354f * erfinv_f(u);
}

// ---------- prep: transposes, exp(v), sampled biases ----------
__global__ __launch_bounds__(256) void prep_kernel(
    const float* __restrict__ x,
    const float* __restrict__ muW1, const float* __restrict__ vW1,
    const float* __restrict__ muW2, const float* __restrict__ vW2,
    const float* __restrict__ mub1, const float* __restrict__ vb1,
    const float* __restrict__ mub2, const float* __restrict__ vb2,
    float* __restrict__ ws,
    uint32_t kb1_0, uint32_t kb1_1, uint32_t kb2_0, uint32_t kb2_1) {
  int t = blockIdx.x * 256 + threadIdx.x;
  if (t < D_IN * D_H) {              // muT1/stdT1: t = i*512 + h
    int i = t >> 9, h = t & 511;
    ws[OFF_MUT1 + t] = muW1[h * D_IN + i];
    ws[OFF_STDT1 + t] = expf(vW1[h * D_IN + i]);
  }
  if (t < D_H * D_OUT) {             // muT2/stdT2: t = hh*256 + o
    int hh = t >> 8, o = t & 255;
    ws[OFF_MUT2 + t] = muW2[o * D_H + hh];
    ws[OFF_STDT2 + t] = expf(vW2[o * D_H + hh]);
  }
  if (t < D_IN * BATCH) {            // xT: t = i*32 + b
    int i = t >> 5, b = t & 31;
    ws[OFF_XT + t] = x[b * D_IN + i];
  }
  if (t < NS * D_H) {                // b1s: t = n*512 + h  (== eb1 flat index)
    int h = t & 511;
    float eps = tf_normal(kb1_0, kb1_1, (uint32_t)t);
    ws[OFF_B1S + t] = fmaf(eps, expf(vb1[h]), mub1[h]);
  }
  if (t < NS * D_OUT) {              // b2s: t = n*256 + o  (== eb2 flat index)
    int o = t & 255;
    float eps = tf_normal(kb2_0, kb2_1, (uint32_t)t);
    ws[OFF_B2S + t] = fmaf(eps, expf(vb2[o]), mub2[o]);
  }
}

// ---------- layer 1: thread = (n, h); 32 batch accumulators ----------
__global__ __launch_bounds__(64) void l1_kernel(
    const float* __restrict__ ws, float* __restrict__ hT,
    uint32_t k0, uint32_t k1) {
  const float* __restrict__ xT = ws + OFF_XT;
  const float* __restrict__ muT1 = ws + OFF_MUT1;
  const float* __restrict__ stdT1 = ws + OFF_STDT1;
  const float* __restrict__ b1s = ws + OFF_B1S;

  int gid = blockIdx.x * 64 + threadIdx.x;     // 0..76799 ; n = gid/512, h = gid%512
  int h = gid & 511;
  float acc[BATCH];
#pragma unroll
  for (int b = 0; b < BATCH; ++b) acc[b] = 0.0f;

  uint32_t base = (uint32_t)gid << 10;         // (n*512+h)*1024 : eW1 flat index base
  for (int i = 0; i < D_IN; ++i) {
    float eps = tf_normal(k0, k1, base + (uint32_t)i);
    float wv = fmaf(eps, stdT1[i * D_H + h], muT1[i * D_H + h]);
    const float4* xp = (const float4*)(xT + i * BATCH);   // wave-uniform address
#pragma unroll
    for (int b4 = 0; b4 < 8; ++b4) {
      float4 xv = xp[b4];
      acc[b4 * 4 + 0] = fmaf(wv, xv.x, acc[b4 * 4 + 0]);
      acc[b4 * 4 + 1] = fmaf(wv, xv.y, acc[b4 * 4 + 1]);
      acc[b4 * 4 + 2] = fmaf(wv, xv.z, acc[b4 * 4 + 2]);
      acc[b4 * 4 + 3] = fmaf(wv, xv.w, acc[b4 * 4 + 3]);
    }
  }
  float bb = b1s[gid];
  float4* hp = (float4*)(hT + (size_t)gid * BATCH);
#pragma unroll
  for (int b4 = 0; b4 < 8; ++b4) {
    float4 o;
    o.x = fmaxf(acc[b4 * 4 + 0] + bb, 0.0f);
    o.y = fmaxf(acc[b4 * 4 + 1] + bb, 0.0f);
    o.z = fmaxf(acc[b4 * 4 + 2] + bb, 0.0f);
    o.w = fmaxf(acc[b4 * 4 + 3] + bb, 0.0f);
    hp[b4] = o;
  }
}

// ---------- layer 2: thread = (n, o); 32 batch accumulators ----------
__global__ __launch_bounds__(64) void l2_kernel(
    const float* __restrict__ ws, float* __restrict__ y,
    uint32_t k0, uint32_t k1) {
  const float* __restrict__ hT = ws + OFF_HT;
  const float* __restrict__ muT2 = ws + OFF_MUT2;
  const float* __restrict__ stdT2 = ws + OFF_STDT2;
  const float* __restrict__ b2s = ws + OFF_B2S;

  int gid = blockIdx.x * 64 + threadIdx.x;     // 0..38399 ; n = gid/256, o = gid%256
  int n = gid >> 8;
  int o = gid & 255;
  float acc[BATCH];
#pragma unroll
  for (int b = 0; b < BATCH; ++b) acc[b] = 0.0f;

  uint32_t base = (uint32_t)gid << 9;          // (n*256+o)*512 : eW2 flat index base
  const float* hbase = hT + (size_t)n * (D_H * BATCH);
  for (int hh = 0; hh < D_H; ++hh) {
    float eps = tf_normal(k0, k1, base + (uint32_t)hh);
    float wv = fmaf(eps, stdT2[hh * D_OUT + o], muT2[hh * D_OUT + o]);
    const float4* hp = (const float4*)(hbase + hh * BATCH);  // wave-uniform address
#pragma unroll
    for (int b4 = 0; b4 < 8; ++b4) {
      float4 hv = hp[b4];
      acc[b4 * 4 + 0] = fmaf(wv, hv.x, acc[b4 * 4 + 0]);
      acc[b4 * 4 + 1] = fmaf(wv, hv.y, acc[b4 * 4 + 1]);
      acc[b4 * 4 + 2] = fmaf(wv, hv.z, acc[b4 * 4 + 2]);
      acc[b4 * 4 + 3] = fmaf(wv, hv.w, acc[b4 * 4 + 3]);
    }
  }
  float bb = b2s[gid];
  float* yb = y + (size_t)n * (BATCH * D_OUT) + o;
#pragma unroll
  for (int b = 0; b < BATCH; ++b) {
    yb[b * D_OUT] = acc[b] + bb;
  }
}

extern "C" void kernel_launch(void* const* d_in, const int* in_sizes, int n_in,
                              void* d_out, int out_size, void* d_ws, size_t ws_size,
                              hipStream_t stream) {
  const float* x = (const float*)d_in[0];
  const float* muW1 = (const float*)d_in[1];
  const float* mub1 = (const float*)d_in[2];
  const float* muW2 = (const float*)d_in[3];
  const float* mub2 = (const float*)d_in[4];
  const float* vW1 = (const float*)d_in[5];
  const float* vb1 = (const float*)d_in[6];
  const float* vW2 = (const float*)d_in[7];
  const float* vb2 = (const float*)d_in[8];
  float* y = (float*)d_out;
  float* ws = (float*)d_ws;

  // split(key(42), 4), partitionable/foldlike: nk[j] = threefry((0,42),(0,j))
  uint32_t nk[4][2];
  for (uint32_t j = 0; j < 4; ++j) {
    threefry2x32(0u, 42u, 0u, j, nk[j][0], nk[j][1]);
  }
  // reference order: eW1=nk[0], eb1=nk[1], eW2=nk[2], eb2=nk[3]

  prep_kernel<<<(D_IN * D_H + 255) / 256, 256, 0, stream>>>(
      x, muW1, vW1, muW2, vW2, mub1, vb1, mub2, vb2, ws,
      nk[1][0], nk[1][1], nk[3][0], nk[3][1]);

  l1_kernel<<<NS * D_H / 64, 64, 0, stream>>>(ws, ws + OFF_HT, nk[0][0], nk[0][1]);

  l2_kernel<<<NS * D_OUT / 64, 64, 0, stream>>>(ws, y, nk[2][0], nk[2][1]);
}

// Round 2
// 771.396 us; speedup vs baseline: 1.9934x; 1.9934x over previous
//
#include <hip/hip_runtime.h>
#include <stdint.h>

#define NS 150
#define D_IN 1024
#define D_H 512
#define D_OUT 256
#define BATCH 32

// ---- workspace layout (float offsets) ----
#define OFF_XT    0u                // 1024*32      = 32768   xT[i][b]
#define OFF_MUT1  32768u            // 1024*512     = 524288  muT1[i][h]
#define OFF_STDT1 557056u           // 524288               stdT1[i][h]
#define OFF_MUT2  1081344u          // 512*256      = 131072  muT2[hh][o]
#define OFF_STDT2 1212416u          // 131072               stdT2[hh][o]
#define OFF_B1S   1343488u          // 150*512      = 76800   b1s[n][h]
#define OFF_B2S   1420288u          // 150*256      = 38400   b2s[n][o]
#define OFF_HT    1458688u          // 150*512*32   = 2457600 hT[n][h][b]
// total = 3,916,288 floats = 15.7 MB

// ---------- threefry-2x32 (JAX-exact, 20 rounds) ----------
__host__ __device__ __forceinline__ void threefry2x32(uint32_t k0, uint32_t k1,
                                                      uint32_t x0, uint32_t x1,
                                                      uint32_t& o0, uint32_t& o1) {
  uint32_t k2 = k0 ^ k1 ^ 0x1BD11BDAu;
  x0 += k0; x1 += k1;
#define TFR(r) { x0 += x1; x1 = (x1 << r) | (x1 >> (32 - r)); x1 ^= x0; }
  TFR(13) TFR(15) TFR(26) TFR(6)
  x0 += k1; x1 += k2 + 1u;
  TFR(17) TFR(29) TFR(16) TFR(24)
  x0 += k2; x1 += k0 + 2u;
  TFR(13) TFR(15) TFR(26) TFR(6)
  x0 += k0; x1 += k1 + 3u;
  TFR(17) TFR(29) TFR(16) TFR(24)
  x0 += k1; x1 += k2 + 4u;
  TFR(13) TFR(15) TFR(26) TFR(6)
  x0 += k2; x1 += k0 + 5u;
#undef TFR
  o0 = x0; o1 = x1;
}

// XLA ErfInv32 (Giles polynomial)
__device__ __forceinline__ float erfinv_f(float x) {
  float w = -log1pf(-x * x);
  float p;
  if (w < 5.0f) {
    w = w - 2.5f;
    p = 2.81022636e-08f;
    p = fmaf(p, w, 3.43273939e-07f);
    p = fmaf(p, w, -3.5233877e-06f);
    p = fmaf(p, w, -4.39150654e-06f);
    p = fmaf(p, w, 0.00021858087f);
    p = fmaf(p, w, -0.00125372503f);
    p = fmaf(p, w, -0.00417768164f);
    p = fmaf(p, w, 0.246640727f);
    p = fmaf(p, w, 1.50140941f);
  } else {
    w = sqrtf(w) - 3.0f;
    p = -0.000200214257f;
    p = fmaf(p, w, 0.000100950558f);
    p = fmaf(p, w, 0.00134934322f);
    p = fmaf(p, w, -0.00367342844f);
    p = fmaf(p, w, 0.00573950773f);
    p = fmaf(p, w, -0.0076224613f);
    p = fmaf(p, w, 0.00943887047f);
    p = fmaf(p, w, 1.00167406f);
    p = fmaf(p, w, 2.83297682f);
  }
  return p * x;
}

__device__ __forceinline__ float tf_normal(uint32_t k0, uint32_t k1, uint32_t idx) {
  uint32_t o0, o1;
  threefry2x32(k0, k1, 0u, idx, o0, o1);
  uint32_t bits = o0 ^ o1;
  uint32_t fb = (bits >> 9) | 0x3F800000u;
  float f = __uint_as_float(fb) - 1.0f;          // [0,1)
  const float lo = -0.99999994f;                 // nextafter(-1,0) in fp32
  float u = fmaf(f, 2.0f, lo);
  u = fmaxf(u, lo);
  return 1.41421354f * erfinv_f(u);
}

// ---------- prep: transposes, exp(v), sampled biases ----------
__global__ __launch_bounds__(256) void prep_kernel(
    const float* __restrict__ x,
    const float* __restrict__ muW1, const float* __restrict__ vW1,
    const float* __restrict__ muW2, const float* __restrict__ vW2,
    const float* __restrict__ mub1, const float* __restrict__ vb1,
    const float* __restrict__ mub2, const float* __restrict__ vb2,
    float* __restrict__ ws,
    uint32_t kb1_0, uint32_t kb1_1, uint32_t kb2_0, uint32_t kb2_1) {
  int t = blockIdx.x * 256 + threadIdx.x;
  if (t < D_IN * D_H) {              // muT1/stdT1: t = i*512 + h
    int i = t >> 9, h = t & 511;
    ws[OFF_MUT1 + t] = muW1[h * D_IN + i];
    ws[OFF_STDT1 + t] = expf(vW1[h * D_IN + i]);
  }
  if (t < D_H * D_OUT) {             // muT2/stdT2: t = hh*256 + o
    int hh = t >> 8, o = t & 255;
    ws[OFF_MUT2 + t] = muW2[o * D_H + hh];
    ws[OFF_STDT2 + t] = expf(vW2[o * D_H + hh]);
  }
  if (t < D_IN * BATCH) {            // xT: t = i*32 + b
    int i = t >> 5, b = t & 31;
    ws[OFF_XT + t] = x[b * D_IN + i];
  }
  if (t < NS * D_H) {                // b1s
    int h = t & 511;
    float eps = tf_normal(kb1_0, kb1_1, (uint32_t)t);
    ws[OFF_B1S + t] = fmaf(eps, expf(vb1[h]), mub1[h]);
  }
  if (t < NS * D_OUT) {              // b2s
    int o = t & 255;
    float eps = tf_normal(kb2_0, kb2_1, (uint32_t)t);
    ws[OFF_B2S + t] = fmaf(eps, expf(vb2[o]), mub2[o]);
  }
}

// ---------- layer 1: block = 256 thr = 4 waves; 64 (n,h) pairs/block,
// each wave handles a 256-wide i-chunk; LDS partial reduce ----------
__global__ __launch_bounds__(256) void l1_kernel(
    const float* __restrict__ ws, float* __restrict__ hT,
    uint32_t k0, uint32_t k1) {
  const float* __restrict__ xT = ws + OFF_XT;
  const float* __restrict__ muT1 = ws + OFF_MUT1;
  const float* __restrict__ stdT1 = ws + OFF_STDT1;
  const float* __restrict__ b1s = ws + OFF_B1S;

  __shared__ float red[4][64][33];   // [chunk][lane][batch], +1 pad vs 32

  int lane = threadIdx.x & 63;
  int wv = threadIdx.x >> 6;                   // chunk 0..3
  int gid = blockIdx.x * 64 + lane;            // (n*512 + h)
  int h = gid & 511;

  float acc[BATCH];
#pragma unroll
  for (int b = 0; b < BATCH; ++b) acc[b] = 0.0f;

  uint32_t base = ((uint32_t)gid << 10) + (uint32_t)(wv * 256);
  int i0 = wv * 256;
#pragma unroll 2
  for (int ii = 0; ii < 256; ++ii) {
    int i = i0 + ii;
    float eps = tf_normal(k0, k1, base + (uint32_t)ii);
    float wval = fmaf(eps, stdT1[i * D_H + h], muT1[i * D_H + h]);
    const float4* xp = (const float4*)(xT + i * BATCH);
#pragma unroll
    for (int b4 = 0; b4 < 8; ++b4) {
      float4 xv = xp[b4];
      acc[b4 * 4 + 0] = fmaf(wval, xv.x, acc[b4 * 4 + 0]);
      acc[b4 * 4 + 1] = fmaf(wval, xv.y, acc[b4 * 4 + 1]);
      acc[b4 * 4 + 2] = fmaf(wval, xv.z, acc[b4 * 4 + 2]);
      acc[b4 * 4 + 3] = fmaf(wval, xv.w, acc[b4 * 4 + 3]);
    }
  }
#pragma unroll
  for (int b = 0; b < BATCH; ++b) red[wv][lane][b] = acc[b];
  __syncthreads();

  // epilogue: thread (wv,lane) handles b in [wv*8, wv*8+8) for gid(lane)
  float bb = b1s[gid];
  float* hp = hT + (size_t)gid * BATCH + wv * 8;
#pragma unroll
  for (int j2 = 0; j2 < 2; ++j2) {
    float4 o;
    int b0 = wv * 8 + j2 * 4;
    o.x = fmaxf(red[0][lane][b0+0] + red[1][lane][b0+0] + red[2][lane][b0+0] + red[3][lane][b0+0] + bb, 0.0f);
    o.y = fmaxf(red[0][lane][b0+1] + red[1][lane][b0+1] + red[2][lane][b0+1] + red[3][lane][b0+1] + bb, 0.0f);
    o.z = fmaxf(red[0][lane][b0+2] + red[1][lane][b0+2] + red[2][lane][b0+2] + red[3][lane][b0+2] + bb, 0.0f);
    o.w = fmaxf(red[0][lane][b0+3] + red[1][lane][b0+3] + red[2][lane][b0+3] + red[3][lane][b0+3] + bb, 0.0f);
    ((float4*)hp)[j2] = o;
  }
}

// ---------- layer 2: block = 256 thr; 32 (n,o) pairs/block, 8 hh-chunks ----------
__global__ __launch_bounds__(256) void l2_kernel(
    const float* __restrict__ ws, float* __restrict__ y,
    uint32_t k0, uint32_t k1) {
  const float* __restrict__ hT = ws + OFF_HT;
  const float* __restrict__ muT2 = ws + OFF_MUT2;
  const float* __restrict__ stdT2 = ws + OFF_STDT2;
  const float* __restrict__ b2s = ws + OFF_B2S;

  __shared__ float red[8][32][33];   // [chunk][g][batch]

  int g = threadIdx.x & 31;
  int c = threadIdx.x >> 5;                    // chunk 0..7
  int gid = blockIdx.x * 32 + g;               // (n*256 + o)
  int n = gid >> 8;
  int o = gid & 255;

  float acc[BATCH];
#pragma unroll
  for (int b = 0; b < BATCH; ++b) acc[b] = 0.0f;

  uint32_t base = ((uint32_t)gid << 9) + (uint32_t)(c * 64);
  int h0 = c * 64;
  const float* hbase = hT + (size_t)n * (D_H * BATCH);
#pragma unroll 2
  for (int jj = 0; jj < 64; ++jj) {
    int hh = h0 + jj;
    float eps = tf_normal(k0, k1, base + (uint32_t)jj);
    float wval = fmaf(eps, stdT2[hh * D_OUT + o], muT2[hh * D_OUT + o]);
    const float4* hp = (const float4*)(hbase + hh * BATCH);
#pragma unroll
    for (int b4 = 0; b4 < 8; ++b4) {
      float4 hv = hp[b4];
      acc[b4 * 4 + 0] = fmaf(wval, hv.x, acc[b4 * 4 + 0]);
      acc[b4 * 4 + 1] = fmaf(wval, hv.y, acc[b4 * 4 + 1]);
      acc[b4 * 4 + 2] = fmaf(wval, hv.z, acc[b4 * 4 + 2]);
      acc[b4 * 4 + 3] = fmaf(wval, hv.w, acc[b4 * 4 + 3]);
    }
  }
#pragma unroll
  for (int b = 0; b < BATCH; ++b) red[c][g][b] = acc[b];
  __syncthreads();

  // epilogue: thread (c,g) handles b in [c*4, c*4+4) for gid(g)
  float bb = b2s[gid];
#pragma unroll
  for (int j = 0; j < 4; ++j) {
    int b = c * 4 + j;
    float s = red[0][g][b] + red[1][g][b] + red[2][g][b] + red[3][g][b]
            + red[4][g][b] + red[5][g][b] + red[6][g][b] + red[7][g][b];
    y[(size_t)n * (BATCH * D_OUT) + b * D_OUT + o] = s + bb;
  }
}

extern "C" void kernel_launch(void* const* d_in, const int* in_sizes, int n_in,
                              void* d_out, int out_size, void* d_ws, size_t ws_size,
                              hipStream_t stream) {
  const float* x = (const float*)d_in[0];
  const float* muW1 = (const float*)d_in[1];
  const float* mub1 = (const float*)d_in[2];
  const float* muW2 = (const float*)d_in[3];
  const float* mub2 = (const float*)d_in[4];
  const float* vW1 = (const float*)d_in[5];
  const float* vb1 = (const float*)d_in[6];
  const float* vW2 = (const float*)d_in[7];
  const float* vb2 = (const float*)d_in[8];
  float* y = (float*)d_out;
  float* ws = (float*)d_ws;

  uint32_t nk[4][2];
  for (uint32_t j = 0; j < 4; ++j) {
    threefry2x32(0u, 42u, 0u, j, nk[j][0], nk[j][1]);
  }
  // eW1=nk[0], eb1=nk[1], eW2=nk[2], eb2=nk[3]

  prep_kernel<<<(D_IN * D_H + 255) / 256, 256, 0, stream>>>(
      x, muW1, vW1, muW2, vW2, mub1, vb1, mub2, vb2, ws,
      nk[1][0], nk[1][1], nk[3][0], nk[3][1]);

  // l1: NS*D_H = 76800 pairs, 64/block, 4 chunks -> 1200 blocks x 256
  l1_kernel<<<NS * D_H / 64, 256, 0, stream>>>(ws, ws + OFF_HT, nk[0][0], nk[0][1]);

  // l2: NS*D_OUT = 38400 pairs, 32/block, 8 chunks -> 1200 blocks x 256
  l2_kernel<<<NS * D_OUT / 32, 256, 0, stream>>>(ws, y, nk[2][0], nk[2][1]);
}

// Round 3
// 504.130 us; speedup vs baseline: 3.0502x; 1.5302x over previous
//
#include <hip/hip_runtime.h>
#include <stdint.h>

#define NS 150
#define D_IN 1024
#define D_H 512
#define D_OUT 256
#define BATCH 32

// ---- workspace layout (float offsets) ----
#define OFF_XT    0u                // 1024*32      = 32768   xT[i][b]
#define OFF_MS1   32768u            // float2[1024*512] (mu,std) at [i][h] -> 1048576 floats
#define OFF_MS2   1081344u          // float2[512*256]  (mu,std) at [hh][o] -> 262144 floats
#define OFF_B1S   1343488u          // 150*512  = 76800   b1s[n][h]
#define OFF_B2S   1420288u          // 150*256  = 38400   b2s[n][o]
#define OFF_HT    1458688u          // 150*512*32 = 2457600  hT[n][h][b]
// total = 3,916,288 floats = 15.7 MB

// ---------- threefry-2x32 (JAX-exact, 20 rounds) ----------
__host__ __device__ __forceinline__ void threefry2x32(uint32_t k0, uint32_t k1,
                                                      uint32_t x0, uint32_t x1,
                                                      uint32_t& o0, uint32_t& o1) {
  uint32_t k2 = k0 ^ k1 ^ 0x1BD11BDAu;
  x0 += k0; x1 += k1;
#define TFR(r) { x0 += x1; x1 = (x1 << r) | (x1 >> (32 - r)); x1 ^= x0; }
  TFR(13) TFR(15) TFR(26) TFR(6)
  x0 += k1; x1 += k2 + 1u;
  TFR(17) TFR(29) TFR(16) TFR(24)
  x0 += k2; x1 += k0 + 2u;
  TFR(13) TFR(15) TFR(26) TFR(6)
  x0 += k0; x1 += k1 + 3u;
  TFR(17) TFR(29) TFR(16) TFR(24)
  x0 += k1; x1 += k2 + 4u;
  TFR(13) TFR(15) TFR(26) TFR(6)
  x0 += k2; x1 += k0 + 5u;
#undef TFR
  o0 = x0; o1 = x1;
}

// bits -> uniform(-1,1) -> sqrt2*erfinv, with NATIVE log2/sqrt.
// w = -ln(1-u^2) via fma (exact product, no cancellation) + v_log_f32.
__device__ __forceinline__ float tf_normal(uint32_t k0, uint32_t k1, uint32_t idx) {
  uint32_t o0, o1;
  threefry2x32(k0, k1, 0u, idx, o0, o1);
  uint32_t bits = o0 ^ o1;
  uint32_t fb = (bits >> 9) | 0x3F800000u;
  float f = __uint_as_float(fb) - 1.0f;          // [0,1)
  const float lo = -0.99999994f;                 // nextafter(-1,0)
  float u = fmaf(f, 2.0f, lo);
  u = fmaxf(u, lo);
  float t = fmaf(u, -u, 1.0f);                   // 1-u^2, single rounding
  float w = -0.69314718056f * __builtin_amdgcn_logf(t);   // -ln(1-u^2)
  float p;
  if (w < 5.0f) {
    float ww = w - 2.5f;
    p = 2.81022636e-08f;
    p = fmaf(p, ww, 3.43273939e-07f);
    p = fmaf(p, ww, -3.5233877e-06f);
    p = fmaf(p, ww, -4.39150654e-06f);
    p = fmaf(p, ww, 0.00021858087f);
    p = fmaf(p, ww, -0.00125372503f);
    p = fmaf(p, ww, -0.00417768164f);
    p = fmaf(p, ww, 0.246640727f);
    p = fmaf(p, ww, 1.50140941f);
  } else {
    float ww = __builtin_amdgcn_sqrtf(w) - 3.0f;
    p = -0.000200214257f;
    p = fmaf(p, ww, 0.000100950558f);
    p = fmaf(p, ww, 0.00134934322f);
    p = fmaf(p, ww, -0.00367342844f);
    p = fmaf(p, ww, 0.00573950773f);
    p = fmaf(p, ww, -0.0076224613f);
    p = fmaf(p, ww, 0.00943887047f);
    p = fmaf(p, ww, 1.00167406f);
    p = fmaf(p, ww, 2.83297682f);
  }
  return 1.41421354f * (p * u);
}

// ---------- prep: LDS-tiled transposes into interleaved (mu,std) + biases ----------
// blocks 0..511   : W1 32x32 tiles  (muW1,vW1 [512h][1024i] -> ms1[i][h] float2)
// blocks 512..639 : W2 32x32 tiles  (muW2,vW2 [256o][512h]  -> ms2[hh][o] float2)
// blocks 640..671 : xT 32x32 tiles  (x [32b][1024i] -> xT[i][b])
// blocks 672..746 : b1s (75*1024 = 76800)
// blocks 747..784 : b2s (38*1024 >= 38400, guarded)
__global__ __launch_bounds__(256) void prep_kernel(
    const float* __restrict__ x,
    const float* __restrict__ muW1, const float* __restrict__ vW1,
    const float* __restrict__ muW2, const float* __restrict__ vW2,
    const float* __restrict__ mub1, const float* __restrict__ vb1,
    const float* __restrict__ mub2, const float* __restrict__ vb2,
    float* __restrict__ ws,
    uint32_t kb1_0, uint32_t kb1_1, uint32_t kb2_0, uint32_t kb2_1) {
  __shared__ float2 tl[32][33];
  int bb = blockIdx.x;
  int tx = threadIdx.x & 31;
  int ty = threadIdx.x >> 5;        // 0..7

  if (bb < 512) {                   // W1 tile: i0 from tile%32, h0 from tile/32
    int i0 = (bb & 31) * 32, h0 = (bb >> 5) * 32;
#pragma unroll
    for (int r = 0; r < 4; ++r) {
      int h = h0 + ty + r * 8, i = i0 + tx;
      float m = muW1[h * D_IN + i];
      float s = expf(vW1[h * D_IN + i]);
      tl[ty + r * 8][tx] = make_float2(m, s);
    }
    __syncthreads();
    float2* ms1 = (float2*)(ws + OFF_MS1);
#pragma unroll
    for (int r = 0; r < 4; ++r) {
      int i = i0 + ty + r * 8, h = h0 + tx;
      ms1[i * D_H + h] = tl[tx][ty + r * 8];
    }
  } else if (bb < 640) {            // W2 tile
    int t = bb - 512;
    int h0 = (t & 15) * 32, o0 = (t >> 4) * 32;
#pragma unroll
    for (int r = 0; r < 4; ++r) {
      int o = o0 + ty + r * 8, hh = h0 + tx;
      float m = muW2[o * D_H + hh];
      float s = expf(vW2[o * D_H + hh]);
      tl[ty + r * 8][tx] = make_float2(m, s);
    }
    __syncthreads();
    float2* ms2 = (float2*)(ws + OFF_MS2);
#pragma unroll
    for (int r = 0; r < 4; ++r) {
      int hh = h0 + ty + r * 8, o = o0 + tx;
      ms2[hh * D_OUT + o] = tl[tx][ty + r * 8];
    }
  } else if (bb < 672) {            // xT tile
    int i0 = (bb - 640) * 32;
#pragma unroll
    for (int r = 0; r < 4; ++r) {
      int b = ty + r * 8, i = i0 + tx;
      tl[ty + r * 8][tx].x = x[b * D_IN + i];
    }
    __syncthreads();
#pragma unroll
    for (int r = 0; r < 4; ++r) {
      int i = i0 + ty + r * 8, b = tx;
      ws[OFF_XT + i * BATCH + b] = tl[tx][ty + r * 8].x;
    }
  } else if (bb < 747) {            // b1s
    int t0 = (bb - 672) * 1024 + threadIdx.x;
#pragma unroll
    for (int r = 0; r < 4; ++r) {
      int t = t0 + r * 256;
      int h = t & 511;
      float eps = tf_normal(kb1_0, kb1_1, (uint32_t)t);
      ws[OFF_B1S + t] = fmaf(eps, expf(vb1[h]), mub1[h]);
    }
  } else {                          // b2s
    int t0 = (bb - 747) * 1024 + threadIdx.x;
#pragma unroll
    for (int r = 0; r < 4; ++r) {
      int t = t0 + r * 256;
      if (t < NS * D_OUT) {
        int o = t & 255;
        float eps = tf_normal(kb2_0, kb2_1, (uint32_t)t);
        ws[OFF_B2S + t] = fmaf(eps, expf(vb2[o]), mub2[o]);
      }
    }
  }
}

// ---------- layer 1: block = 256 thr = 4 waves; 64 (n,h) pairs/block,
// each wave a 256-wide i-chunk; LDS partial reduce. LDS = exactly 32 KiB
// -> 5 blocks/CU, all 1200 blocks resident in one pass. ----------
__global__ __launch_bounds__(256) void l1_kernel(
    const float* __restrict__ ws, float* __restrict__ hT,
    uint32_t k0, uint32_t k1) {
  const float* __restrict__ xT = ws + OFF_XT;
  const float2* __restrict__ ms1 = (const float2*)(ws + OFF_MS1);
  const float* __restrict__ b1s = ws + OFF_B1S;

  __shared__ float red[4][64][32];   // 32768 B exactly; epilogue-only use

  int lane = threadIdx.x & 63;
  int wv = threadIdx.x >> 6;                   // chunk 0..3
  int gid = blockIdx.x * 64 + lane;            // (n*512 + h)
  int h = gid & 511;

  float acc[BATCH];
#pragma unroll
  for (int b = 0; b < BATCH; ++b) acc[b] = 0.0f;

  uint32_t base = ((uint32_t)gid << 10) + (uint32_t)(wv * 256);
  int i0 = wv * 256;
#pragma unroll 2
  for (int ii = 0; ii < 256; ++ii) {
    int i = i0 + ii;
    float2 ms = ms1[i * D_H + h];              // one dwordx2 load
    float eps = tf_normal(k0, k1, base + (uint32_t)ii);
    float wval = fmaf(eps, ms.y, ms.x);
    const float4* xp = (const float4*)(xT + i * BATCH);   // wave-uniform -> s_load
#pragma unroll
    for (int b4 = 0; b4 < 8; ++b4) {
      float4 xv = xp[b4];
      acc[b4 * 4 + 0] = fmaf(wval, xv.x, acc[b4 * 4 + 0]);
      acc[b4 * 4 + 1] = fmaf(wval, xv.y, acc[b4 * 4 + 1]);
      acc[b4 * 4 + 2] = fmaf(wval, xv.z, acc[b4 * 4 + 2]);
      acc[b4 * 4 + 3] = fmaf(wval, xv.w, acc[b4 * 4 + 3]);
    }
  }
#pragma unroll
  for (int b = 0; b < BATCH; ++b) red[wv][lane][b] = acc[b];
  __syncthreads();

  float bb = b1s[gid];
  float* hp = hT + (size_t)gid * BATCH + wv * 8;
#pragma unroll
  for (int j2 = 0; j2 < 2; ++j2) {
    float4 o;
    int b0 = wv * 8 + j2 * 4;
    o.x = fmaxf(red[0][lane][b0+0] + red[1][lane][b0+0] + red[2][lane][b0+0] + red[3][lane][b0+0] + bb, 0.0f);
    o.y = fmaxf(red[0][lane][b0+1] + red[1][lane][b0+1] + red[2][lane][b0+1] + red[3][lane][b0+1] + bb, 0.0f);
    o.z = fmaxf(red[0][lane][b0+2] + red[1][lane][b0+2] + red[2][lane][b0+2] + red[3][lane][b0+2] + bb, 0.0f);
    o.w = fmaxf(red[0][lane][b0+3] + red[1][lane][b0+3] + red[2][lane][b0+3] + red[3][lane][b0+3] + bb, 0.0f);
    ((float4*)hp)[j2] = o;
  }
}

// ---------- layer 2: block = 256 thr; 32 (n,o) pairs/block, 8 hh-chunks ----------
__global__ __launch_bounds__(256) void l2_kernel(
    const float* __restrict__ ws, float* __restrict__ y,
    uint32_t k0, uint32_t k1) {
  const float* __restrict__ hT = ws + OFF_HT;
  const float2* __restrict__ ms2 = (const float2*)(ws + OFF_MS2);
  const float* __restrict__ b2s = ws + OFF_B2S;

  __shared__ float red[8][32][32];   // 32768 B exactly

  int g = threadIdx.x & 31;
  int c = threadIdx.x >> 5;                    // chunk 0..7
  int gid = blockIdx.x * 32 + g;               // (n*256 + o)
  int n = gid >> 8;
  int o = gid & 255;

  float acc[BATCH];
#pragma unroll
  for (int b = 0; b < BATCH; ++b) acc[b] = 0.0f;

  uint32_t base = ((uint32_t)gid << 9) + (uint32_t)(c * 64);
  int h0 = c * 64;
  const float* hbase = hT + (size_t)n * (D_H * BATCH);
#pragma unroll 2
  for (int jj = 0; jj < 64; ++jj) {
    int hh = h0 + jj;
    float2 ms = ms2[hh * D_OUT + o];
    float eps = tf_normal(k0, k1, base + (uint32_t)jj);
    float wval = fmaf(eps, ms.y, ms.x);
    const float4* hp = (const float4*)(hbase + hh * BATCH);  // wave-uniform
#pragma unroll
    for (int b4 = 0; b4 < 8; ++b4) {
      float4 hv = hp[b4];
      acc[b4 * 4 + 0] = fmaf(wval, hv.x, acc[b4 * 4 + 0]);
      acc[b4 * 4 + 1] = fmaf(wval, hv.y, acc[b4 * 4 + 1]);
      acc[b4 * 4 + 2] = fmaf(wval, hv.z, acc[b4 * 4 + 2]);
      acc[b4 * 4 + 3] = fmaf(wval, hv.w, acc[b4 * 4 + 3]);
    }
  }
#pragma unroll
  for (int b = 0; b < BATCH; ++b) red[c][g][b] = acc[b];
  __syncthreads();

  float bb = b2s[gid];
#pragma unroll
  for (int j = 0; j < 4; ++j) {
    int b = c * 4 + j;
    float s = red[0][g][b] + red[1][g][b] + red[2][g][b] + red[3][g][b]
            + red[4][g][b] + red[5][g][b] + red[6][g][b] + red[7][g][b];
    y[(size_t)n * (BATCH * D_OUT) + b * D_OUT + o] = s + bb;
  }
}

extern "C" void kernel_launch(void* const* d_in, const int* in_sizes, int n_in,
                              void* d_out, int out_size, void* d_ws, size_t ws_size,
                              hipStream_t stream) {
  const float* x = (const float*)d_in[0];
  const float* muW1 = (const float*)d_in[1];
  const float* mub1 = (const float*)d_in[2];
  const float* muW2 = (const float*)d_in[3];
  const float* mub2 = (const float*)d_in[4];
  const float* vW1 = (const float*)d_in[5];
  const float* vb1 = (const float*)d_in[6];
  const float* vW2 = (const float*)d_in[7];
  const float* vb2 = (const float*)d_in[8];
  float* y = (float*)d_out;
  float* ws = (float*)d_ws;

  uint32_t nk[4][2];
  for (uint32_t j = 0; j < 4; ++j) {
    threefry2x32(0u, 42u, 0u, j, nk[j][0], nk[j][1]);
  }
  // eW1=nk[0], eb1=nk[1], eW2=nk[2], eb2=nk[3]

  prep_kernel<<<785, 256, 0, stream>>>(
      x, muW1, vW1, muW2, vW2, mub1, vb1, mub2, vb2, ws,
      nk[1][0], nk[1][1], nk[3][0], nk[3][1]);

  // l1: 76800 (n,h) pairs, 64/block, 4 i-chunks -> 1200 blocks x 256
  l1_kernel<<<NS * D_H / 64, 256, 0, stream>>>(ws, ws + OFF_HT, nk[0][0], nk[0][1]);

  // l2: 38400 (n,o) pairs, 32/block, 8 hh-chunks -> 1200 blocks x 256
  l2_kernel<<<NS * D_OUT / 32, 256, 0, stream>>>(ws, y, nk[2][0], nk[2][1]);
}

// Round 4
// 431.114 us; speedup vs baseline: 3.5668x; 1.1694x over previous
//
#include <hip/hip_runtime.h>
#include <stdint.h>

#define NS 150
#define D_IN 1024
#define D_H 512
#define D_OUT 256
#define BATCH 32

// ---- workspace layout (float offsets) ----
#define OFF_XT    0u                // 1024*32      = 32768   xT[i][b]
#define OFF_MS1   32768u            // float2[1024*512] (mu,std) at [i][h] -> 1048576 floats
#define OFF_MS2   1081344u          // float2[512*256]  (mu,std) at [hh][o] -> 262144 floats
#define OFF_B1S   1343488u          // 150*512  = 76800   b1s[n][h]
#define OFF_B2S   1420288u          // 150*256  = 38400   b2s[n][o]
#define OFF_HT    1458688u          // 150*512*32 = 2457600  hT[n][h][b]
// total = 3,916,288 floats = 15.7 MB

// ---------- threefry-2x32 (JAX-exact, 20 rounds) ----------
__host__ __device__ __forceinline__ void threefry2x32(uint32_t k0, uint32_t k1,
                                                      uint32_t x0, uint32_t x1,
                                                      uint32_t& o0, uint32_t& o1) {
  uint32_t k2 = k0 ^ k1 ^ 0x1BD11BDAu;
  x0 += k0; x1 += k1;
#define TFR(r) { x0 += x1; x1 = (x1 << r) | (x1 >> (32 - r)); x1 ^= x0; }
  TFR(13) TFR(15) TFR(26) TFR(6)
  x0 += k1; x1 += k2 + 1u;
  TFR(17) TFR(29) TFR(16) TFR(24)
  x0 += k2; x1 += k0 + 2u;
  TFR(13) TFR(15) TFR(26) TFR(6)
  x0 += k0; x1 += k1 + 3u;
  TFR(17) TFR(29) TFR(16) TFR(24)
  x0 += k1; x1 += k2 + 4u;
  TFR(13) TFR(15) TFR(26) TFR(6)
  x0 += k2; x1 += k0 + 5u;
#undef TFR
  o0 = x0; o1 = x1;
}

// bits -> uniform(-1,1) -> sqrt2*erfinv, native log/sqrt
__device__ __forceinline__ float tf_normal(uint32_t k0, uint32_t k1, uint32_t idx) {
  uint32_t o0, o1;
  threefry2x32(k0, k1, 0u, idx, o0, o1);
  uint32_t bits = o0 ^ o1;
  uint32_t fb = (bits >> 9) | 0x3F800000u;
  float f = __uint_as_float(fb) - 1.0f;          // [0,1)
  const float lo = -0.99999994f;                 // nextafter(-1,0)
  float u = fmaf(f, 2.0f, lo);
  u = fmaxf(u, lo);
  float t = fmaf(u, -u, 1.0f);                   // 1-u^2, single rounding
  float w = -0.69314718056f * __builtin_amdgcn_logf(t);   // -ln(1-u^2)
  float p;
  if (w < 5.0f) {
    float ww = w - 2.5f;
    p = 2.81022636e-08f;
    p = fmaf(p, ww, 3.43273939e-07f);
    p = fmaf(p, ww, -3.5233877e-06f);
    p = fmaf(p, ww, -4.39150654e-06f);
    p = fmaf(p, ww, 0.00021858087f);
    p = fmaf(p, ww, -0.00125372503f);
    p = fmaf(p, ww, -0.00417768164f);
    p = fmaf(p, ww, 0.246640727f);
    p = fmaf(p, ww, 1.50140941f);
  } else {
    float ww = __builtin_amdgcn_sqrtf(w) - 3.0f;
    p = -0.000200214257f;
    p = fmaf(p, ww, 0.000100950558f);
    p = fmaf(p, ww, 0.00134934322f);
    p = fmaf(p, ww, -0.00367342844f);
    p = fmaf(p, ww, 0.00573950773f);
    p = fmaf(p, ww, -0.0076224613f);
    p = fmaf(p, ww, 0.00943887047f);
    p = fmaf(p, ww, 1.00167406f);
    p = fmaf(p, ww, 2.83297682f);
  }
  return 1.41421354f * (p * u);
}

// ---------- prep: LDS-tiled transposes into interleaved (mu,std) + biases ----------
__global__ __launch_bounds__(256) void prep_kernel(
    const float* __restrict__ x,
    const float* __restrict__ muW1, const float* __restrict__ vW1,
    const float* __restrict__ muW2, const float* __restrict__ vW2,
    const float* __restrict__ mub1, const float* __restrict__ vb1,
    const float* __restrict__ mub2, const float* __restrict__ vb2,
    float* __restrict__ ws,
    uint32_t kb1_0, uint32_t kb1_1, uint32_t kb2_0, uint32_t kb2_1) {
  __shared__ float2 tl[32][33];
  int bb = blockIdx.x;
  int tx = threadIdx.x & 31;
  int ty = threadIdx.x >> 5;        // 0..7

  if (bb < 512) {                   // W1 tile
    int i0 = (bb & 31) * 32, h0 = (bb >> 5) * 32;
#pragma unroll
    for (int r = 0; r < 4; ++r) {
      int h = h0 + ty + r * 8, i = i0 + tx;
      float m = muW1[h * D_IN + i];
      float s = expf(vW1[h * D_IN + i]);
      tl[ty + r * 8][tx] = make_float2(m, s);
    }
    __syncthreads();
    float2* ms1 = (float2*)(ws + OFF_MS1);
#pragma unroll
    for (int r = 0; r < 4; ++r) {
      int i = i0 + ty + r * 8, h = h0 + tx;
      ms1[i * D_H + h] = tl[tx][ty + r * 8];
    }
  } else if (bb < 640) {            // W2 tile
    int t = bb - 512;
    int h0 = (t & 15) * 32, o0 = (t >> 4) * 32;
#pragma unroll
    for (int r = 0; r < 4; ++r) {
      int o = o0 + ty + r * 8, hh = h0 + tx;
      float m = muW2[o * D_H + hh];
      float s = expf(vW2[o * D_H + hh]);
      tl[ty + r * 8][tx] = make_float2(m, s);
    }
    __syncthreads();
    float2* ms2 = (float2*)(ws + OFF_MS2);
#pragma unroll
    for (int r = 0; r < 4; ++r) {
      int hh = h0 + ty + r * 8, o = o0 + tx;
      ms2[hh * D_OUT + o] = tl[tx][ty + r * 8];
    }
  } else if (bb < 672) {            // xT tile
    int i0 = (bb - 640) * 32;
#pragma unroll
    for (int r = 0; r < 4; ++r) {
      int b = ty + r * 8, i = i0 + tx;
      tl[ty + r * 8][tx].x = x[b * D_IN + i];
    }
    __syncthreads();
#pragma unroll
    for (int r = 0; r < 4; ++r) {
      int i = i0 + ty + r * 8, b = tx;
      ws[OFF_XT + i * BATCH + b] = tl[tx][ty + r * 8].x;
    }
  } else if (bb < 747) {            // b1s
    int t0 = (bb - 672) * 1024 + threadIdx.x;
#pragma unroll
    for (int r = 0; r < 4; ++r) {
      int t = t0 + r * 256;
      int h = t & 511;
      float eps = tf_normal(kb1_0, kb1_1, (uint32_t)t);
      ws[OFF_B1S + t] = fmaf(eps, expf(vb1[h]), mub1[h]);
    }
  } else {                          // b2s
    int t0 = (bb - 747) * 1024 + threadIdx.x;
#pragma unroll
    for (int r = 0; r < 4; ++r) {
      int t = t0 + r * 256;
      if (t < NS * D_OUT) {
        int o = t & 255;
        float eps = tf_normal(kb2_0, kb2_1, (uint32_t)t);
        ws[OFF_B2S + t] = fmaf(eps, expf(vb2[o]), mub2[o]);
      }
    }
  }
}

// ---------- layer 1: block = 512 thr = 8 waves; 64 (n,h)/block, 8 i-chunks of 128.
// LDS = 16 KiB (4-pass b-sliced reduce, [chunk][b][lane] = conflict-free)
// -> wave-cap 4 blocks/CU = 32 waves/CU. ----------
__global__ __launch_bounds__(512, 8) void l1_kernel(
    const float* __restrict__ ws, float* __restrict__ hT,
    uint32_t k0, uint32_t k1) {
  const float* __restrict__ xT = ws + OFF_XT;
  const float2* __restrict__ ms1 = (const float2*)(ws + OFF_MS1);
  const float* __restrict__ b1s = ws + OFF_B1S;

  __shared__ float red[8][8][64];    // 16384 B; [chunk][b-slice][lane]

  int lane = threadIdx.x & 63;
  int wv = __builtin_amdgcn_readfirstlane(threadIdx.x >> 6);   // chunk 0..7, SGPR
  int gid = blockIdx.x * 64 + lane;            // (n*512 + h)
  int h = gid & 511;

  float acc[BATCH];
#pragma unroll
  for (int b = 0; b < BATCH; ++b) acc[b] = 0.0f;

  uint32_t base = ((uint32_t)gid << 10) + (uint32_t)(wv * 128);
  int i0 = wv * 128;
#pragma unroll 2
  for (int ii = 0; ii < 128; ++ii) {
    int i = i0 + ii;                            // wave-uniform
    float2 ms = ms1[i * D_H + h];               // per-lane dwordx2, coalesced
    float eps = tf_normal(k0, k1, base + (uint32_t)ii);
    float wval = fmaf(eps, ms.y, ms.x);
    const float4* xp = (const float4*)(xT + i * BATCH);   // wave-uniform addr
#pragma unroll
    for (int b4 = 0; b4 < 8; ++b4) {
      float4 xv = xp[b4];
      acc[b4 * 4 + 0] = fmaf(wval, xv.x, acc[b4 * 4 + 0]);
      acc[b4 * 4 + 1] = fmaf(wval, xv.y, acc[b4 * 4 + 1]);
      acc[b4 * 4 + 2] = fmaf(wval, xv.z, acc[b4 * 4 + 2]);
      acc[b4 * 4 + 3] = fmaf(wval, xv.w, acc[b4 * 4 + 3]);
    }
  }

  float bb = b1s[gid];
#pragma unroll
  for (int p = 0; p < 4; ++p) {
#pragma unroll
    for (int j = 0; j < 8; ++j) red[wv][j][lane] = acc[p * 8 + j];
    __syncthreads();
    // thread (wv,lane) reduces b = p*8 + wv for gid(lane')... each (wv,lane)
    // handles output (gid=block*64+lane, b=p*8+wv)
    float s = red[0][wv][lane] + red[1][wv][lane] + red[2][wv][lane] + red[3][wv][lane]
            + red[4][wv][lane] + red[5][wv][lane] + red[6][wv][lane] + red[7][wv][lane];
    hT[(size_t)gid * BATCH + p * 8 + wv] = fmaxf(s + bb, 0.0f);
    __syncthreads();
  }
}

// ---------- layer 2: block = 1024 thr = 16 waves; 64 (n,o)/block, 16 hh-chunks of 32.
// LDS = 32 KiB (4-pass b-sliced reduce) -> wave-cap 2 blocks/CU = 32 waves/CU. ----------
__global__ __launch_bounds__(1024, 8) void l2_kernel(
    const float* __restrict__ ws, float* __restrict__ y,
    uint32_t k0, uint32_t k1) {
  const float* __restrict__ hT = ws + OFF_HT;
  const float2* __restrict__ ms2 = (const float2*)(ws + OFF_MS2);
  const float* __restrict__ b2s = ws + OFF_B2S;

  __shared__ float red[16][8][64];   // 32768 B; [chunk][b-slice][lane]

  int lane = threadIdx.x & 63;
  int c = __builtin_amdgcn_readfirstlane(threadIdx.x >> 6);    // chunk 0..15
  int gid = blockIdx.x * 64 + lane;            // (n*256 + o)
  int n = __builtin_amdgcn_readfirstlane(gid >> 8);  // wave-uniform (64 | 256)
  int o = gid & 255;

  float acc[BATCH];
#pragma unroll
  for (int b = 0; b < BATCH; ++b) acc[b] = 0.0f;

  uint32_t base = ((uint32_t)gid << 9) + (uint32_t)(c * 32);
  int h0 = c * 32;
  const float* hbase = hT + (size_t)n * (D_H * BATCH);
#pragma unroll 2
  for (int jj = 0; jj < 32; ++jj) {
    int hh = h0 + jj;                           // wave-uniform
    float2 ms = ms2[hh * D_OUT + o];            // per-lane, coalesced
    float eps = tf_normal(k0, k1, base + (uint32_t)jj);
    float wval = fmaf(eps, ms.y, ms.x);
    const float4* hp = (const float4*)(hbase + hh * BATCH);   // wave-uniform addr
#pragma unroll
    for (int b4 = 0; b4 < 8; ++b4) {
      float4 hv = hp[b4];
      acc[b4 * 4 + 0] = fmaf(wval, hv.x, acc[b4 * 4 + 0]);
      acc[b4 * 4 + 1] = fmaf(wval, hv.y, acc[b4 * 4 + 1]);
      acc[b4 * 4 + 2] = fmaf(wval, hv.z, acc[b4 * 4 + 2]);
      acc[b4 * 4 + 3] = fmaf(wval, hv.w, acc[b4 * 4 + 3]);
    }
  }

  float bb = b2s[gid];
#pragma unroll
  for (int p = 0; p < 4; ++p) {
#pragma unroll
    for (int j = 0; j < 8; ++j) red[c][j][lane] = acc[p * 8 + j];
    __syncthreads();
    if (c < 8) {                                // waves 0..7 reduce b = p*8 + c
      float s = 0.0f;
#pragma unroll
      for (int cc = 0; cc < 16; ++cc) s += red[cc][c][lane];
      int b = p * 8 + c;
      y[(size_t)n * (BATCH * D_OUT) + b * D_OUT + o] = s + bb;   // coalesced (o inner)
    }
    __syncthreads();
  }
}

extern "C" void kernel_launch(void* const* d_in, const int* in_sizes, int n_in,
                              void* d_out, int out_size, void* d_ws, size_t ws_size,
                              hipStream_t stream) {
  const float* x = (const float*)d_in[0];
  const float* muW1 = (const float*)d_in[1];
  const float* mub1 = (const float*)d_in[2];
  const float* muW2 = (const float*)d_in[3];
  const float* mub2 = (const float*)d_in[4];
  const float* vW1 = (const float*)d_in[5];
  const float* vb1 = (const float*)d_in[6];
  const float* vW2 = (const float*)d_in[7];
  const float* vb2 = (const float*)d_in[8];
  float* y = (float*)d_out;
  float* ws = (float*)d_ws;

  uint32_t nk[4][2];
  for (uint32_t j = 0; j < 4; ++j) {
    threefry2x32(0u, 42u, 0u, j, nk[j][0], nk[j][1]);
  }
  // eW1=nk[0], eb1=nk[1], eW2=nk[2], eb2=nk[3]

  prep_kernel<<<785, 256, 0, stream>>>(
      x, muW1, vW1, muW2, vW2, mub1, vb1, mub2, vb2, ws,
      nk[1][0], nk[1][1], nk[3][0], nk[3][1]);

  // l1: 76800 (n,h) pairs, 64/block, 8 i-chunks -> 1200 blocks x 512
  l1_kernel<<<NS * D_H / 64, 512, 0, stream>>>(ws, ws + OFF_HT, nk[0][0], nk[0][1]);

  // l2: 38400 (n,o) pairs, 64/block, 16 hh-chunks -> 600 blocks x 1024
  l2_kernel<<<NS * D_OUT / 64, 1024, 0, stream>>>(ws, y, nk[2][0], nk[2][1]);
}